// Round 2
// 3878.220 us; speedup vs baseline: 1.0010x; 1.0010x over previous
//
#include <hip/hip_runtime.h>
#include <stdint.h>

// LSTM: B=32, S=1024, I=H=512, 4H=2048
// Phase 1: x_gates = x @ W_ih^T + (b_ih + b_hh)   [bf16 MFMA GEMM]
// Phase 2: persistent cooperative kernel, 8 groups x 32 WGs; W_hh slice in
//          REGISTERS (pinned via asm "+v" barrier), h in LDS, h exchanged via
//          global double buffer + per-group padded counter, all RELAXED
//          agent-scope atomics (ordering from __syncthreads' vmcnt(0) drain).
// Round-3 note: the pin loop MUST be #pragma unroll'd. Un-unrolled, the
//          runtime-indexed W[i] inside the asm forces the whole W[128] array
//          into scratch (runtime-indexed arrays -> local memory), giving the
//          VGPR=92 / FETCH=531MB signature measured in rounds 0-2. This
//          round changes ONLY that (round 1's bundled sync restructure
//          introduced a race and is reverted wholesale).

typedef __attribute__((ext_vector_type(8))) short bf16x8;
typedef __attribute__((ext_vector_type(4))) float f32x4;

__device__ __forceinline__ unsigned short f2bf(float f) {
  union { float f; unsigned u; } v; v.f = f;
  unsigned r = (v.u + 0x7fffu + ((v.u >> 16) & 1u)) >> 16;  // RNE
  return (unsigned short)r;
}
__device__ __forceinline__ float bf2f(unsigned short h) {
  union { unsigned u; float f; } v; v.u = ((unsigned)h) << 16;
  return v.f;
}

__global__ __launch_bounds__(256) void cvt_bf16(const float* __restrict__ in,
                                                unsigned short* __restrict__ out, int n) {
  int i = (blockIdx.x * 256 + threadIdx.x) * 4;
  if (i >= n) return;
  float4 v = *(const float4*)(in + i);
  ushort4 o;
  o.x = f2bf(v.x); o.y = f2bf(v.y); o.z = f2bf(v.z); o.w = f2bf(v.w);
  *(ushort4*)(out + i) = o;
}

// C[m][n] = sum_k A[m][k]*B[n][k] + b_ih[n] + b_hh[n], stored bf16.
__global__ __launch_bounds__(256) void gemm_xg(const unsigned short* __restrict__ A,
                                               const unsigned short* __restrict__ Bw,
                                               const float* __restrict__ b_ih,
                                               const float* __restrict__ b_hh,
                                               unsigned short* __restrict__ xg) {
  __shared__ unsigned short Asub[128][32];
  __shared__ unsigned short Bsub[128][32];
  const int tid = threadIdx.x;
  const int mb = blockIdx.x >> 4;
  const int nb = blockIdx.x & 15;
  const int wv = tid >> 6, ln = tid & 63;
  const int wr = wv >> 1, wc = wv & 1;
  const int lrow = tid >> 1;
  const int lseg = (tid & 1) * 16;

  const unsigned short* Ag = A + (size_t)(mb * 128 + lrow) * 512 + lseg;
  const unsigned short* Bg = Bw + (size_t)(nb * 128 + lrow) * 512 + lseg;

  f32x4 acc[4][4] = {};
  const int frow = ln & 15;
  const int kq = (ln >> 4) * 8;

  for (int k0 = 0; k0 < 512; k0 += 32) {
    uint4 a0 = *(const uint4*)(Ag + k0);
    uint4 a1 = *(const uint4*)(Ag + k0 + 8);
    uint4 b0 = *(const uint4*)(Bg + k0);
    uint4 b1 = *(const uint4*)(Bg + k0 + 8);
    __syncthreads();
    *(uint4*)&Asub[lrow][lseg]     = a0;
    *(uint4*)&Asub[lrow][lseg + 8] = a1;
    *(uint4*)&Bsub[lrow][lseg]     = b0;
    *(uint4*)&Bsub[lrow][lseg + 8] = b1;
    __syncthreads();
    bf16x8 af[4], bfr[4];
#pragma unroll
    for (int mi = 0; mi < 4; ++mi)
      af[mi] = *(const bf16x8*)&Asub[wr * 64 + mi * 16 + frow][kq];
#pragma unroll
    for (int ni = 0; ni < 4; ++ni)
      bfr[ni] = *(const bf16x8*)&Bsub[wc * 64 + ni * 16 + frow][kq];
#pragma unroll
    for (int mi = 0; mi < 4; ++mi)
#pragma unroll
      for (int ni = 0; ni < 4; ++ni)
        acc[mi][ni] = __builtin_amdgcn_mfma_f32_16x16x32_bf16(af[mi], bfr[ni], acc[mi][ni], 0, 0, 0);
  }

  const int col0 = nb * 128 + wc * 64 + frow;
  float bias[4];
#pragma unroll
  for (int ni = 0; ni < 4; ++ni)
    bias[ni] = b_ih[col0 + ni * 16] + b_hh[col0 + ni * 16];

#pragma unroll
  for (int mi = 0; mi < 4; ++mi) {
    const int m0 = mb * 128 + wr * 64 + mi * 16 + (ln >> 4) * 4;
#pragma unroll
    for (int ni = 0; ni < 4; ++ni) {
#pragma unroll
      for (int rr = 0; rr < 4; ++rr) {
        float v = acc[mi][ni][rr] + bias[ni];
        xg[(size_t)(m0 + rr) * 2048 + col0 + ni * 16] = f2bf(v);
      }
    }
  }
}

// Persistent recurrent kernel. Grid = 256 WGs (8 groups x 32), 256 threads.
// Group g owns batches [4g,4g+4); WG w owns h-indices [16w,16w+16).
// Thread (kc=tid>>6, r=tid&63) holds W_hh[row(r)][kc*128 .. +128) in registers.
__global__ __launch_bounds__(256, 1) void lstm_rec(const unsigned short* __restrict__ xg,
                                                   const float* __restrict__ W_hh,
                                                   const float* __restrict__ h0,
                                                   const float* __restrict__ c0,
                                                   float* __restrict__ out,
                                                   float* __restrict__ hn,
                                                   float* __restrict__ cn,
                                                   float* h_buf,        // [2][32][512]
                                                   unsigned int* cnt) { // [8], stride 64 uints
  __shared__ float h_lds[2048];
  __shared__ float scratch[64 * 17];
  __shared__ float gates_lds[64 * 5];
  __shared__ float c_lds[64];

  const int tid = threadIdx.x;
  const int g = blockIdx.x >> 5;
  const int w = blockIdx.x & 31;
  const int gb0 = g * 4;
  const int kc = tid >> 6;
  const int r = tid & 63;
  const int grow = (r >> 4) * 512 + w * 16 + (r & 15);
  const int kcb = kc * 128;
  unsigned int* my_cnt = cnt + g * 64;  // 256B stride: no false sharing

  // One-time W_hh slice load, then PIN in VGPRs. The pin loop is fully
  // unrolled: any runtime-indexed access to W forces the array to scratch.
  float W[128];
  {
    const float* wp = W_hh + (size_t)grow * 512 + kcb;
#pragma unroll
    for (int i = 0; i < 128; i += 4) {
      float4 v = *(const float4*)(wp + i);
      W[i] = v.x; W[i + 1] = v.y; W[i + 2] = v.z; W[i + 3] = v.w;
    }
  }
#pragma unroll
  for (int i = 0; i < 128; ++i) asm volatile("" : "+v"(W[i]));

  {
    const float* hp = h0 + gb0 * 512 + tid * 8;
    float4 va = *(const float4*)hp;
    float4 vb = *(const float4*)(hp + 4);
    *(float4*)&h_lds[tid * 8] = va;
    *(float4*)&h_lds[tid * 8 + 4] = vb;
    if (tid < 64) {
      int jj = tid & 15, bb = tid >> 4;
      c_lds[bb * 16 + jj] = c0[(gb0 + bb) * 512 + w * 16 + jj];
    }
  }
  __syncthreads();

  for (int t = 0; t < 1024; ++t) {
    // Issued at loop top, consumed after the FMA loop -> latency hidden.
    float xg_v = bf2f(xg[(size_t)((gb0 + kc) * 1024 + t) * 2048 + grow]);

    float acc0 = 0.f, acc1 = 0.f, acc2 = 0.f, acc3 = 0.f;
#pragma unroll
    for (int i = 0; i < 128; i += 4) {
      float4 ha = *(const float4*)&h_lds[kcb + i];
      float4 hb = *(const float4*)&h_lds[512 + kcb + i];
      float4 hc = *(const float4*)&h_lds[1024 + kcb + i];
      float4 hd = *(const float4*)&h_lds[1536 + kcb + i];
      acc0 = fmaf(W[i], ha.x, acc0); acc0 = fmaf(W[i + 1], ha.y, acc0);
      acc0 = fmaf(W[i + 2], ha.z, acc0); acc0 = fmaf(W[i + 3], ha.w, acc0);
      acc1 = fmaf(W[i], hb.x, acc1); acc1 = fmaf(W[i + 1], hb.y, acc1);
      acc1 = fmaf(W[i + 2], hb.z, acc1); acc1 = fmaf(W[i + 3], hb.w, acc1);
      acc2 = fmaf(W[i], hc.x, acc2); acc2 = fmaf(W[i + 1], hc.y, acc2);
      acc2 = fmaf(W[i + 2], hc.z, acc2); acc2 = fmaf(W[i + 3], hc.w, acc2);
      acc3 = fmaf(W[i], hd.x, acc3); acc3 = fmaf(W[i + 1], hd.y, acc3);
      acc3 = fmaf(W[i + 2], hd.z, acc3); acc3 = fmaf(W[i + 3], hd.w, acc3);
    }
    scratch[r * 17 + kc] = acc0;
    scratch[r * 17 + 4 + kc] = acc1;
    scratch[r * 17 + 8 + kc] = acc2;
    scratch[r * 17 + 12 + kc] = acc3;
    __syncthreads();

    {
      float s = xg_v + scratch[r * 17 + kc * 4] + scratch[r * 17 + kc * 4 + 1]
                     + scratch[r * 17 + kc * 4 + 2] + scratch[r * 17 + kc * 4 + 3];
      gates_lds[r * 5 + kc] = s;
    }
    __syncthreads();

    if (tid < 64) {
      const int jj = tid & 15, bb = tid >> 4;
      float gi = gates_lds[jj * 5 + bb];
      float gf = gates_lds[(16 + jj) * 5 + bb];
      float gc = gates_lds[(32 + jj) * 5 + bb];
      float go = gates_lds[(48 + jj) * 5 + bb];
      float ig = 1.f / (1.f + __expf(-gi));
      float fg = 1.f / (1.f + __expf(-gf));
      float gt = tanhf(gc);
      float og = 1.f / (1.f + __expf(-go));
      float c = fmaf(fg, c_lds[bb * 16 + jj], ig * gt);
      c_lds[bb * 16 + jj] = c;
      float hv = og * tanhf(c);
      out[(size_t)((gb0 + bb) * 1024 + t) * 512 + w * 16 + jj] = hv;
      __hip_atomic_store(&h_buf[((t + 1) & 1) * 16384 + (gb0 + bb) * 512 + w * 16 + jj], hv,
                         __ATOMIC_RELAXED, __HIP_MEMORY_SCOPE_AGENT);
      if (t == 1023) {
        hn[(gb0 + bb) * 512 + w * 16 + jj] = hv;
        cn[(gb0 + bb) * 512 + w * 16 + jj] = c;
      }
    }
    __syncthreads();  // s_waitcnt vmcnt(0) before s_barrier: h stores are at LLC

    if (t < 1023) {
      if (tid == 0) {
        __hip_atomic_fetch_add(my_cnt, 1u, __ATOMIC_RELAXED, __HIP_MEMORY_SCOPE_AGENT);
        const unsigned target = 32u * (unsigned)(t + 1);
        while (__hip_atomic_load(my_cnt, __ATOMIC_RELAXED, __HIP_MEMORY_SCOPE_AGENT) < target)
          __builtin_amdgcn_s_sleep(2);
      }
      __syncthreads();
      // Stage next h into LDS; 8-byte relaxed atomic loads (4 VMEM ops).
      const unsigned long long* hb =
          (const unsigned long long*)(h_buf + ((t + 1) & 1) * 16384 + gb0 * 512 + tid * 8);
      unsigned long long v[4];
#pragma unroll
      for (int q = 0; q < 4; ++q)
        v[q] = __hip_atomic_load(hb + q, __ATOMIC_RELAXED, __HIP_MEMORY_SCOPE_AGENT);
#pragma unroll
      for (int q = 0; q < 4; ++q)
        *(unsigned long long*)&h_lds[tid * 8 + q * 2] = v[q];
      __syncthreads();
    }
  }
}

extern "C" void kernel_launch(void* const* d_in, const int* in_sizes, int n_in,
                              void* d_out, int out_size, void* d_ws, size_t ws_size,
                              hipStream_t stream) {
  const float* x    = (const float*)d_in[0];
  const float* W_ih = (const float*)d_in[1];
  const float* W_hh = (const float*)d_in[2];
  const float* b_ih = (const float*)d_in[3];
  const float* b_hh = (const float*)d_in[4];
  const float* h0   = (const float*)d_in[5];
  const float* c0   = (const float*)d_in[6];
  float* out = (float*)d_out;
  float* hn = out + (size_t)32 * 1024 * 512;
  float* cn = hn + 32 * 512;

  uint8_t* ws = (uint8_t*)d_ws;
  unsigned short* xg   = (unsigned short*)ws;                   // 134,217,728 B
  unsigned short* x_bf = (unsigned short*)(ws + 134217728u);    //  33,554,432 B
  unsigned short* w_bf = (unsigned short*)(ws + 167772160u);    //   2,097,152 B
  float* h_buf         = (float*)(ws + 169869312u);             //     131,072 B
  unsigned int* cnt    = (unsigned int*)(ws + 170000384u);      //  8 * 256 B

  hipMemsetAsync(cnt, 0, 8 * 256, stream);
  cvt_bf16<<<dim3(16384), dim3(256), 0, stream>>>(x, x_bf, 16777216);
  cvt_bf16<<<dim3(1024), dim3(256), 0, stream>>>(W_ih, w_bf, 1048576);
  gemm_xg<<<dim3(4096), dim3(256), 0, stream>>>(x_bf, w_bf, b_ih, b_hh, xg);

  void* args[] = {(void*)&xg, (void*)&W_hh, (void*)&h0, (void*)&c0,
                  (void*)&out, (void*)&hn, (void*)&cn, (void*)&h_buf, (void*)&cnt};
  hipLaunchCooperativeKernel((const void*)lstm_rec, dim3(256), dim3(256), args, 0, stream);
}

// Round 4
// 3387.593 us; speedup vs baseline: 1.1459x; 1.1448x over previous
//
#include <hip/hip_runtime.h>
#include <stdint.h>

// LSTM: B=32, S=1024, I=H=512, 4H=2048
// Phase 1: x_gates = x @ W_ih^T + (b_ih + b_hh)   [bf16 MFMA GEMM]
// Phase 2: persistent cooperative kernel, 8 groups x 32 WGs x 512 threads.
//   Counters proved the 128-floats-per-thread W pin never held (VGPR=92,
//   FETCH=531MB: regalloc spills 128 live-through values to scratch; the
//   scratch re-reads thrash L2 -> ~360MB excess HBM fetch). Fix by SHRINKING
//   THE ASK: kc=tid>>6 owns a 64-wide k-chunk -> W[64] per thread, 8 partials
//   reduced in LDS. Sync/exchange protocol unchanged from the passing r2
//   kernel. (r3 failed only due to a stray leftover scratch-store line that
//   raced with legitimate writes — removed here; no other change.)

typedef __attribute__((ext_vector_type(8))) short bf16x8;
typedef __attribute__((ext_vector_type(4))) float f32x4;

__device__ __forceinline__ unsigned short f2bf(float f) {
  union { float f; unsigned u; } v; v.f = f;
  unsigned r = (v.u + 0x7fffu + ((v.u >> 16) & 1u)) >> 16;  // RNE
  return (unsigned short)r;
}
__device__ __forceinline__ float bf2f(unsigned short h) {
  union { unsigned u; float f; } v; v.u = ((unsigned)h) << 16;
  return v.f;
}

__global__ __launch_bounds__(256) void cvt_bf16(const float* __restrict__ in,
                                                unsigned short* __restrict__ out, int n) {
  int i = (blockIdx.x * 256 + threadIdx.x) * 4;
  if (i >= n) return;
  float4 v = *(const float4*)(in + i);
  ushort4 o;
  o.x = f2bf(v.x); o.y = f2bf(v.y); o.z = f2bf(v.z); o.w = f2bf(v.w);
  *(ushort4*)(out + i) = o;
}

// C[m][n] = sum_k A[m][k]*B[n][k] + b_ih[n] + b_hh[n], stored bf16.
__global__ __launch_bounds__(256) void gemm_xg(const unsigned short* __restrict__ A,
                                               const unsigned short* __restrict__ Bw,
                                               const float* __restrict__ b_ih,
                                               const float* __restrict__ b_hh,
                                               unsigned short* __restrict__ xg) {
  __shared__ unsigned short Asub[128][32];
  __shared__ unsigned short Bsub[128][32];
  const int tid = threadIdx.x;
  const int mb = blockIdx.x >> 4;
  const int nb = blockIdx.x & 15;
  const int wv = tid >> 6, ln = tid & 63;
  const int wr = wv >> 1, wc = wv & 1;
  const int lrow = tid >> 1;
  const int lseg = (tid & 1) * 16;

  const unsigned short* Ag = A + (size_t)(mb * 128 + lrow) * 512 + lseg;
  const unsigned short* Bg = Bw + (size_t)(nb * 128 + lrow) * 512 + lseg;

  f32x4 acc[4][4] = {};
  const int frow = ln & 15;
  const int kq = (ln >> 4) * 8;

  for (int k0 = 0; k0 < 512; k0 += 32) {
    uint4 a0 = *(const uint4*)(Ag + k0);
    uint4 a1 = *(const uint4*)(Ag + k0 + 8);
    uint4 b0 = *(const uint4*)(Bg + k0);
    uint4 b1 = *(const uint4*)(Bg + k0 + 8);
    __syncthreads();
    *(uint4*)&Asub[lrow][lseg]     = a0;
    *(uint4*)&Asub[lrow][lseg + 8] = a1;
    *(uint4*)&Bsub[lrow][lseg]     = b0;
    *(uint4*)&Bsub[lrow][lseg + 8] = b1;
    __syncthreads();
    bf16x8 af[4], bfr[4];
#pragma unroll
    for (int mi = 0; mi < 4; ++mi)
      af[mi] = *(const bf16x8*)&Asub[wr * 64 + mi * 16 + frow][kq];
#pragma unroll
    for (int ni = 0; ni < 4; ++ni)
      bfr[ni] = *(const bf16x8*)&Bsub[wc * 64 + ni * 16 + frow][kq];
#pragma unroll
    for (int mi = 0; mi < 4; ++mi)
#pragma unroll
      for (int ni = 0; ni < 4; ++ni)
        acc[mi][ni] = __builtin_amdgcn_mfma_f32_16x16x32_bf16(af[mi], bfr[ni], acc[mi][ni], 0, 0, 0);
  }

  const int col0 = nb * 128 + wc * 64 + frow;
  float bias[4];
#pragma unroll
  for (int ni = 0; ni < 4; ++ni)
    bias[ni] = b_ih[col0 + ni * 16] + b_hh[col0 + ni * 16];

#pragma unroll
  for (int mi = 0; mi < 4; ++mi) {
    const int m0 = mb * 128 + wr * 64 + mi * 16 + (ln >> 4) * 4;
#pragma unroll
    for (int ni = 0; ni < 4; ++ni) {
#pragma unroll
      for (int rr = 0; rr < 4; ++rr) {
        float v = acc[mi][ni][rr] + bias[ni];
        xg[(size_t)(m0 + rr) * 2048 + col0 + ni * 16] = f2bf(v);
      }
    }
  }
}

// Persistent recurrent kernel. Grid = 256 WGs (8 groups x 32), 512 threads.
// Group g owns batches [4g,4g+4); WG w owns h-indices [16w,16w+16) -> 64
// gate-rows. Thread (kc=tid>>6 in [0,8), r=tid&63) holds
// W_hh[grow(r)][kc*64 .. +64) in registers (64 floats).
__global__ __launch_bounds__(512, 1) void lstm_rec(const unsigned short* __restrict__ xg,
                                                   const float* __restrict__ W_hh,
                                                   const float* __restrict__ h0,
                                                   const float* __restrict__ c0,
                                                   float* __restrict__ out,
                                                   float* __restrict__ hn,
                                                   float* __restrict__ cn,
                                                   float* h_buf,        // [2][32][512]
                                                   unsigned int* cnt) { // [8], stride 64 uints
  __shared__ float h_lds[2048];
  __shared__ float scratch[2048];      // [batch(4)][kc(8)][row(64)]
  __shared__ float gates_lds[64 * 5];  // [row(64)][batch(4)+pad]
  __shared__ float c_lds[64];

  const int tid = threadIdx.x;   // 0..511
  const int g = blockIdx.x >> 5;
  const int w = blockIdx.x & 31;
  const int gb0 = g * 4;
  const int kc = tid >> 6;       // 0..7: 64-wide k-chunk
  const int r = tid & 63;        // row within WG's 64 rows
  const int grow = (r >> 4) * 512 + w * 16 + (r & 15);
  const int kcb = kc * 64;
  unsigned int* my_cnt = cnt + g * 64;  // 256B stride: no false sharing

  // One-time W_hh slice load (64 floats/thread), pinned against re-load.
  float W[64];
  {
    const float* wp = W_hh + (size_t)grow * 512 + kcb;
#pragma unroll
    for (int i = 0; i < 64; i += 4) {
      float4 v = *(const float4*)(wp + i);
      W[i] = v.x; W[i + 1] = v.y; W[i + 2] = v.z; W[i + 3] = v.w;
    }
  }
#pragma unroll
  for (int i = 0; i < 64; ++i) asm volatile("" : "+v"(W[i]));

  {
    *(float4*)&h_lds[tid * 4] = *(const float4*)(h0 + gb0 * 512 + tid * 4);
    if (tid < 64) {
      int jj = tid & 15, bb = tid >> 4;
      c_lds[bb * 16 + jj] = c0[(gb0 + bb) * 512 + w * 16 + jj];
    }
  }
  __syncthreads();

  // Identity for the reduce phase (threads 0..255): wave bb2 handles batch bb2.
  const int rr = tid & 63, bb2 = tid >> 6;
  const int grow_r = (rr >> 4) * 512 + w * 16 + (rr & 15);

  for (int t = 0; t < 1024; ++t) {
    // Issued at loop top, consumed in the reduce phase -> latency hidden.
    float xg_v = 0.f;
    if (tid < 256)
      xg_v = bf2f(xg[(size_t)((gb0 + bb2) * 1024 + t) * 2048 + grow_r]);

    float acc0 = 0.f, acc1 = 0.f, acc2 = 0.f, acc3 = 0.f;
#pragma unroll
    for (int i = 0; i < 64; i += 4) {
      float4 ha = *(const float4*)&h_lds[kcb + i];
      float4 hb = *(const float4*)&h_lds[512 + kcb + i];
      float4 hc = *(const float4*)&h_lds[1024 + kcb + i];
      float4 hd = *(const float4*)&h_lds[1536 + kcb + i];
      acc0 = fmaf(W[i], ha.x, acc0); acc0 = fmaf(W[i + 1], ha.y, acc0);
      acc0 = fmaf(W[i + 2], ha.z, acc0); acc0 = fmaf(W[i + 3], ha.w, acc0);
      acc1 = fmaf(W[i], hb.x, acc1); acc1 = fmaf(W[i + 1], hb.y, acc1);
      acc1 = fmaf(W[i + 2], hb.z, acc1); acc1 = fmaf(W[i + 3], hb.w, acc1);
      acc2 = fmaf(W[i], hc.x, acc2); acc2 = fmaf(W[i + 1], hc.y, acc2);
      acc2 = fmaf(W[i + 2], hc.z, acc2); acc2 = fmaf(W[i + 3], hc.w, acc2);
      acc3 = fmaf(W[i], hd.x, acc3); acc3 = fmaf(W[i + 1], hd.y, acc3);
      acc3 = fmaf(W[i + 2], hd.z, acc3); acc3 = fmaf(W[i + 3], hd.w, acc3);
    }
    // scratch[bb][kc][r]: writes are lane-consecutive (conflict-free).
    scratch[0 * 512 + kc * 64 + r] = acc0;
    scratch[1 * 512 + kc * 64 + r] = acc1;
    scratch[2 * 512 + kc * 64 + r] = acc2;
    scratch[3 * 512 + kc * 64 + r] = acc3;
    __syncthreads();

    if (tid < 256) {
      const float* sp = &scratch[bb2 * 512 + rr];
      float s = xg_v;
#pragma unroll
      for (int q = 0; q < 8; ++q) s += sp[q * 64];
      gates_lds[rr * 5 + bb2] = s;
    }
    __syncthreads();

    if (tid < 64) {
      const int jj = tid & 15, bb = tid >> 4;
      float gi = gates_lds[jj * 5 + bb];
      float gf = gates_lds[(16 + jj) * 5 + bb];
      float gc = gates_lds[(32 + jj) * 5 + bb];
      float go = gates_lds[(48 + jj) * 5 + bb];
      float ig = 1.f / (1.f + __expf(-gi));
      float fg = 1.f / (1.f + __expf(-gf));
      float gt = tanhf(gc);
      float og = 1.f / (1.f + __expf(-go));
      float c = fmaf(fg, c_lds[bb * 16 + jj], ig * gt);
      c_lds[bb * 16 + jj] = c;
      float hv = og * tanhf(c);
      out[(size_t)((gb0 + bb) * 1024 + t) * 512 + w * 16 + jj] = hv;
      __hip_atomic_store(&h_buf[((t + 1) & 1) * 16384 + (gb0 + bb) * 512 + w * 16 + jj], hv,
                         __ATOMIC_RELAXED, __HIP_MEMORY_SCOPE_AGENT);
      if (t == 1023) {
        hn[(gb0 + bb) * 512 + w * 16 + jj] = hv;
        cn[(gb0 + bb) * 512 + w * 16 + jj] = c;
      }
    }
    __syncthreads();  // s_waitcnt vmcnt(0) before s_barrier: h stores are at LLC

    if (t < 1023) {
      if (tid == 0) {
        __hip_atomic_fetch_add(my_cnt, 1u, __ATOMIC_RELAXED, __HIP_MEMORY_SCOPE_AGENT);
        const unsigned target = 32u * (unsigned)(t + 1);
        while (__hip_atomic_load(my_cnt, __ATOMIC_RELAXED, __HIP_MEMORY_SCOPE_AGENT) < target)
          __builtin_amdgcn_s_sleep(2);
      }
      __syncthreads();
      // Stage next h into LDS; 8-byte relaxed atomic loads (2 VMEM ops/thread).
      const unsigned long long* hb =
          (const unsigned long long*)(h_buf + ((t + 1) & 1) * 16384 + gb0 * 512 + tid * 4);
      unsigned long long v0 = __hip_atomic_load(hb,     __ATOMIC_RELAXED, __HIP_MEMORY_SCOPE_AGENT);
      unsigned long long v1 = __hip_atomic_load(hb + 1, __ATOMIC_RELAXED, __HIP_MEMORY_SCOPE_AGENT);
      *(unsigned long long*)&h_lds[tid * 4]     = v0;
      *(unsigned long long*)&h_lds[tid * 4 + 2] = v1;
      __syncthreads();
    }
  }
}

extern "C" void kernel_launch(void* const* d_in, const int* in_sizes, int n_in,
                              void* d_out, int out_size, void* d_ws, size_t ws_size,
                              hipStream_t stream) {
  const float* x    = (const float*)d_in[0];
  const float* W_ih = (const float*)d_in[1];
  const float* W_hh = (const float*)d_in[2];
  const float* b_ih = (const float*)d_in[3];
  const float* b_hh = (const float*)d_in[4];
  const float* h0   = (const float*)d_in[5];
  const float* c0   = (const float*)d_in[6];
  float* out = (float*)d_out;
  float* hn = out + (size_t)32 * 1024 * 512;
  float* cn = hn + 32 * 512;

  uint8_t* ws = (uint8_t*)d_ws;
  unsigned short* xg   = (unsigned short*)ws;                   // 134,217,728 B
  unsigned short* x_bf = (unsigned short*)(ws + 134217728u);    //  33,554,432 B
  unsigned short* w_bf = (unsigned short*)(ws + 167772160u);    //   2,097,152 B
  float* h_buf         = (float*)(ws + 169869312u);             //     131,072 B
  unsigned int* cnt    = (unsigned int*)(ws + 170000384u);      //  8 * 256 B

  hipMemsetAsync(cnt, 0, 8 * 256, stream);
  cvt_bf16<<<dim3(16384), dim3(256), 0, stream>>>(x, x_bf, 16777216);
  cvt_bf16<<<dim3(1024), dim3(256), 0, stream>>>(W_ih, w_bf, 1048576);
  gemm_xg<<<dim3(4096), dim3(256), 0, stream>>>(x_bf, w_bf, b_ih, b_hh, xg);

  void* args[] = {(void*)&xg, (void*)&W_hh, (void*)&h0, (void*)&c0,
                  (void*)&out, (void*)&hn, (void*)&cn, (void*)&h_buf, (void*)&cnt};
  hipLaunchCooperativeKernel((const void*)lstm_rec, dim3(256), dim3(512), args, 0, stream);
}

// Round 5
// 3359.974 us; speedup vs baseline: 1.1554x; 1.0082x over previous
//
#include <hip/hip_runtime.h>
#include <stdint.h>

// LSTM: B=32, S=1024, I=H=512, 4H=2048
// Phase 1: x_gates = x @ W_ih^T + (b_ih + b_hh)   [bf16 MFMA GEMM]
// Phase 2: persistent cooperative kernel, 8 groups x 32 WGs x 512 threads.
//   History: float W[64] + per-element asm pin STILL spilled (r4: VGPR=60,
//   FETCH=531MB — the asm pins a value only AT the statement, not its live
//   range; the 33.5MB scratch working set re-read each step = the ~365MB
//   excess HBM fetch). r5 fix: W as 16 NAMED f32x4 values (no array ->
//   nothing scratch-allocatable), one multi-operand asm pin, macro-unrolled
//   FMA. Sync protocol byte-identical to passing r4.

typedef __attribute__((ext_vector_type(8))) short bf16x8;
typedef __attribute__((ext_vector_type(4))) float f32x4;

__device__ __forceinline__ unsigned short f2bf(float f) {
  union { float f; unsigned u; } v; v.f = f;
  unsigned r = (v.u + 0x7fffu + ((v.u >> 16) & 1u)) >> 16;  // RNE
  return (unsigned short)r;
}
__device__ __forceinline__ float bf2f(unsigned short h) {
  union { unsigned u; float f; } v; v.u = ((unsigned)h) << 16;
  return v.f;
}

__global__ __launch_bounds__(256) void cvt_bf16(const float* __restrict__ in,
                                                unsigned short* __restrict__ out, int n) {
  int i = (blockIdx.x * 256 + threadIdx.x) * 4;
  if (i >= n) return;
  float4 v = *(const float4*)(in + i);
  ushort4 o;
  o.x = f2bf(v.x); o.y = f2bf(v.y); o.z = f2bf(v.z); o.w = f2bf(v.w);
  *(ushort4*)(out + i) = o;
}

// C[m][n] = sum_k A[m][k]*B[n][k] + b_ih[n] + b_hh[n], stored bf16.
__global__ __launch_bounds__(256) void gemm_xg(const unsigned short* __restrict__ A,
                                               const unsigned short* __restrict__ Bw,
                                               const float* __restrict__ b_ih,
                                               const float* __restrict__ b_hh,
                                               unsigned short* __restrict__ xg) {
  __shared__ unsigned short Asub[128][32];
  __shared__ unsigned short Bsub[128][32];
  const int tid = threadIdx.x;
  const int mb = blockIdx.x >> 4;
  const int nb = blockIdx.x & 15;
  const int wv = tid >> 6, ln = tid & 63;
  const int wr = wv >> 1, wc = wv & 1;
  const int lrow = tid >> 1;
  const int lseg = (tid & 1) * 16;

  const unsigned short* Ag = A + (size_t)(mb * 128 + lrow) * 512 + lseg;
  const unsigned short* Bg = Bw + (size_t)(nb * 128 + lrow) * 512 + lseg;

  f32x4 acc[4][4] = {};
  const int frow = ln & 15;
  const int kq = (ln >> 4) * 8;

  for (int k0 = 0; k0 < 512; k0 += 32) {
    uint4 a0 = *(const uint4*)(Ag + k0);
    uint4 a1 = *(const uint4*)(Ag + k0 + 8);
    uint4 b0 = *(const uint4*)(Bg + k0);
    uint4 b1 = *(const uint4*)(Bg + k0 + 8);
    __syncthreads();
    *(uint4*)&Asub[lrow][lseg]     = a0;
    *(uint4*)&Asub[lrow][lseg + 8] = a1;
    *(uint4*)&Bsub[lrow][lseg]     = b0;
    *(uint4*)&Bsub[lrow][lseg + 8] = b1;
    __syncthreads();
    bf16x8 af[4], bfr[4];
#pragma unroll
    for (int mi = 0; mi < 4; ++mi)
      af[mi] = *(const bf16x8*)&Asub[wr * 64 + mi * 16 + frow][kq];
#pragma unroll
    for (int ni = 0; ni < 4; ++ni)
      bfr[ni] = *(const bf16x8*)&Bsub[wc * 64 + ni * 16 + frow][kq];
#pragma unroll
    for (int mi = 0; mi < 4; ++mi)
#pragma unroll
      for (int ni = 0; ni < 4; ++ni)
        acc[mi][ni] = __builtin_amdgcn_mfma_f32_16x16x32_bf16(af[mi], bfr[ni], acc[mi][ni], 0, 0, 0);
  }

  const int col0 = nb * 128 + wc * 64 + frow;
  float bias[4];
#pragma unroll
  for (int ni = 0; ni < 4; ++ni)
    bias[ni] = b_ih[col0 + ni * 16] + b_hh[col0 + ni * 16];

#pragma unroll
  for (int mi = 0; mi < 4; ++mi) {
    const int m0 = mb * 128 + wr * 64 + mi * 16 + (ln >> 4) * 4;
#pragma unroll
    for (int ni = 0; ni < 4; ++ni) {
#pragma unroll
      for (int rr = 0; rr < 4; ++rr) {
        float v = acc[mi][ni][rr] + bias[ni];
        xg[(size_t)(m0 + rr) * 2048 + col0 + ni * 16] = f2bf(v);
      }
    }
  }
}

// One 4-wide k-chunk of the four batch dot-products.
// WV: f32x4 of W_hh[grow][kcb+4q .. +4); h chunks read broadcast per wave.
#define FMA_BLK(q, WV)                                                        \
  do {                                                                        \
    f32x4 ha = *(const f32x4*)&h_lds[kcb + (q) * 4];                          \
    f32x4 hb = *(const f32x4*)&h_lds[512 + kcb + (q) * 4];                    \
    f32x4 hc = *(const f32x4*)&h_lds[1024 + kcb + (q) * 4];                   \
    f32x4 hd = *(const f32x4*)&h_lds[1536 + kcb + (q) * 4];                   \
    acc0 = fmaf(WV.x, ha.x, acc0); acc0 = fmaf(WV.y, ha.y, acc0);             \
    acc0 = fmaf(WV.z, ha.z, acc0); acc0 = fmaf(WV.w, ha.w, acc0);             \
    acc1 = fmaf(WV.x, hb.x, acc1); acc1 = fmaf(WV.y, hb.y, acc1);             \
    acc1 = fmaf(WV.z, hb.z, acc1); acc1 = fmaf(WV.w, hb.w, acc1);             \
    acc2 = fmaf(WV.x, hc.x, acc2); acc2 = fmaf(WV.y, hc.y, acc2);             \
    acc2 = fmaf(WV.z, hc.z, acc2); acc2 = fmaf(WV.w, hc.w, acc2);             \
    acc3 = fmaf(WV.x, hd.x, acc3); acc3 = fmaf(WV.y, hd.y, acc3);             \
    acc3 = fmaf(WV.z, hd.z, acc3); acc3 = fmaf(WV.w, hd.w, acc3);             \
  } while (0)

// Persistent recurrent kernel. Grid = 256 WGs (8 groups x 32), 512 threads.
// Group g owns batches [4g,4g+4); WG w owns h-indices [16w,16w+16) -> 64
// gate-rows. Thread (kc=tid>>6 in [0,8), r=tid&63) holds
// W_hh[grow(r)][kc*64 .. +64) in 16 named f32x4 registers.
__global__ __launch_bounds__(512, 1) void lstm_rec(const unsigned short* __restrict__ xg,
                                                   const float* __restrict__ W_hh,
                                                   const float* __restrict__ h0,
                                                   const float* __restrict__ c0,
                                                   float* __restrict__ out,
                                                   float* __restrict__ hn,
                                                   float* __restrict__ cn,
                                                   float* h_buf,        // [2][32][512]
                                                   unsigned int* cnt) { // [8], stride 64 uints
  __shared__ float h_lds[2048];
  __shared__ float scratch[2048];      // [batch(4)][kc(8)][row(64)]
  __shared__ float gates_lds[64 * 5];  // [row(64)][batch(4)+pad]
  __shared__ float c_lds[64];

  const int tid = threadIdx.x;   // 0..511
  const int g = blockIdx.x >> 5;
  const int w = blockIdx.x & 31;
  const int gb0 = g * 4;
  const int kc = tid >> 6;       // 0..7: 64-wide k-chunk
  const int r = tid & 63;        // row within WG's 64 rows
  const int grow = (r >> 4) * 512 + w * 16 + (r & 15);
  const int kcb = kc * 64;
  unsigned int* my_cnt = cnt + g * 64;  // 256B stride: no false sharing

  // One-time W_hh slice load into 16 NAMED f32x4 values — not an array, so
  // regalloc has no scratch-allocation escape hatch. Single asm pin keeps
  // the loads hoisted out of the t-loop.
  const float* wp = W_hh + (size_t)grow * 512 + kcb;
  f32x4 W0  = *(const f32x4*)(wp + 0),  W1  = *(const f32x4*)(wp + 4);
  f32x4 W2  = *(const f32x4*)(wp + 8),  W3  = *(const f32x4*)(wp + 12);
  f32x4 W4  = *(const f32x4*)(wp + 16), W5  = *(const f32x4*)(wp + 20);
  f32x4 W6  = *(const f32x4*)(wp + 24), W7  = *(const f32x4*)(wp + 28);
  f32x4 W8  = *(const f32x4*)(wp + 32), W9  = *(const f32x4*)(wp + 36);
  f32x4 W10 = *(const f32x4*)(wp + 40), W11 = *(const f32x4*)(wp + 44);
  f32x4 W12 = *(const f32x4*)(wp + 48), W13 = *(const f32x4*)(wp + 52);
  f32x4 W14 = *(const f32x4*)(wp + 56), W15 = *(const f32x4*)(wp + 60);
  asm volatile("" : "+v"(W0), "+v"(W1), "+v"(W2), "+v"(W3),
                    "+v"(W4), "+v"(W5), "+v"(W6), "+v"(W7),
                    "+v"(W8), "+v"(W9), "+v"(W10), "+v"(W11),
                    "+v"(W12), "+v"(W13), "+v"(W14), "+v"(W15));

  {
    *(float4*)&h_lds[tid * 4] = *(const float4*)(h0 + gb0 * 512 + tid * 4);
    if (tid < 64) {
      int jj = tid & 15, bb = tid >> 4;
      c_lds[bb * 16 + jj] = c0[(gb0 + bb) * 512 + w * 16 + jj];
    }
  }
  __syncthreads();

  // Identity for the reduce phase (threads 0..255): wave bb2 handles batch bb2.
  const int rr = tid & 63, bb2 = tid >> 6;
  const int grow_r = (rr >> 4) * 512 + w * 16 + (rr & 15);

  for (int t = 0; t < 1024; ++t) {
    // Issued at loop top, consumed in the reduce phase -> latency hidden.
    float xg_v = 0.f;
    if (tid < 256)
      xg_v = bf2f(xg[(size_t)((gb0 + bb2) * 1024 + t) * 2048 + grow_r]);

    float acc0 = 0.f, acc1 = 0.f, acc2 = 0.f, acc3 = 0.f;
    FMA_BLK(0, W0);   FMA_BLK(1, W1);   FMA_BLK(2, W2);   FMA_BLK(3, W3);
    FMA_BLK(4, W4);   FMA_BLK(5, W5);   FMA_BLK(6, W6);   FMA_BLK(7, W7);
    FMA_BLK(8, W8);   FMA_BLK(9, W9);   FMA_BLK(10, W10); FMA_BLK(11, W11);
    FMA_BLK(12, W12); FMA_BLK(13, W13); FMA_BLK(14, W14); FMA_BLK(15, W15);

    // scratch[bb][kc][r]: writes are lane-consecutive (conflict-free).
    scratch[0 * 512 + kc * 64 + r] = acc0;
    scratch[1 * 512 + kc * 64 + r] = acc1;
    scratch[2 * 512 + kc * 64 + r] = acc2;
    scratch[3 * 512 + kc * 64 + r] = acc3;
    __syncthreads();

    if (tid < 256) {
      const float* sp = &scratch[bb2 * 512 + rr];
      float s = xg_v;
#pragma unroll
      for (int q = 0; q < 8; ++q) s += sp[q * 64];
      gates_lds[rr * 5 + bb2] = s;
    }
    __syncthreads();

    if (tid < 64) {
      const int jj = tid & 15, bb = tid >> 4;
      float gi = gates_lds[jj * 5 + bb];
      float gf = gates_lds[(16 + jj) * 5 + bb];
      float gc = gates_lds[(32 + jj) * 5 + bb];
      float go = gates_lds[(48 + jj) * 5 + bb];
      float ig = 1.f / (1.f + __expf(-gi));
      float fg = 1.f / (1.f + __expf(-gf));
      float gt = tanhf(gc);
      float og = 1.f / (1.f + __expf(-go));
      float c = fmaf(fg, c_lds[bb * 16 + jj], ig * gt);
      c_lds[bb * 16 + jj] = c;
      float hv = og * tanhf(c);
      out[(size_t)((gb0 + bb) * 1024 + t) * 512 + w * 16 + jj] = hv;
      __hip_atomic_store(&h_buf[((t + 1) & 1) * 16384 + (gb0 + bb) * 512 + w * 16 + jj], hv,
                         __ATOMIC_RELAXED, __HIP_MEMORY_SCOPE_AGENT);
      if (t == 1023) {
        hn[(gb0 + bb) * 512 + w * 16 + jj] = hv;
        cn[(gb0 + bb) * 512 + w * 16 + jj] = c;
      }
    }
    __syncthreads();  // s_waitcnt vmcnt(0) before s_barrier: h stores are at LLC

    if (t < 1023) {
      if (tid == 0) {
        __hip_atomic_fetch_add(my_cnt, 1u, __ATOMIC_RELAXED, __HIP_MEMORY_SCOPE_AGENT);
        const unsigned target = 32u * (unsigned)(t + 1);
        while (__hip_atomic_load(my_cnt, __ATOMIC_RELAXED, __HIP_MEMORY_SCOPE_AGENT) < target)
          __builtin_amdgcn_s_sleep(2);
      }
      __syncthreads();
      // Stage next h into LDS; 8-byte relaxed atomic loads (2 VMEM ops/thread).
      const unsigned long long* hb =
          (const unsigned long long*)(h_buf + ((t + 1) & 1) * 16384 + gb0 * 512 + tid * 4);
      unsigned long long v0 = __hip_atomic_load(hb,     __ATOMIC_RELAXED, __HIP_MEMORY_SCOPE_AGENT);
      unsigned long long v1 = __hip_atomic_load(hb + 1, __ATOMIC_RELAXED, __HIP_MEMORY_SCOPE_AGENT);
      *(unsigned long long*)&h_lds[tid * 4]     = v0;
      *(unsigned long long*)&h_lds[tid * 4 + 2] = v1;
      __syncthreads();
    }
  }
}

extern "C" void kernel_launch(void* const* d_in, const int* in_sizes, int n_in,
                              void* d_out, int out_size, void* d_ws, size_t ws_size,
                              hipStream_t stream) {
  const float* x    = (const float*)d_in[0];
  const float* W_ih = (const float*)d_in[1];
  const float* W_hh = (const float*)d_in[2];
  const float* b_ih = (const float*)d_in[3];
  const float* b_hh = (const float*)d_in[4];
  const float* h0   = (const float*)d_in[5];
  const float* c0   = (const float*)d_in[6];
  float* out = (float*)d_out;
  float* hn = out + (size_t)32 * 1024 * 512;
  float* cn = hn + 32 * 512;

  uint8_t* ws = (uint8_t*)d_ws;
  unsigned short* xg   = (unsigned short*)ws;                   // 134,217,728 B
  unsigned short* x_bf = (unsigned short*)(ws + 134217728u);    //  33,554,432 B
  unsigned short* w_bf = (unsigned short*)(ws + 167772160u);    //   2,097,152 B
  float* h_buf         = (float*)(ws + 169869312u);             //     131,072 B
  unsigned int* cnt    = (unsigned int*)(ws + 170000384u);      //  8 * 256 B

  hipMemsetAsync(cnt, 0, 8 * 256, stream);
  cvt_bf16<<<dim3(16384), dim3(256), 0, stream>>>(x, x_bf, 16777216);
  cvt_bf16<<<dim3(1024), dim3(256), 0, stream>>>(W_ih, w_bf, 1048576);
  gemm_xg<<<dim3(4096), dim3(256), 0, stream>>>(x_bf, w_bf, b_ih, b_hh, xg);

  void* args[] = {(void*)&xg, (void*)&W_hh, (void*)&h0, (void*)&c0,
                  (void*)&out, (void*)&hn, (void*)&cn, (void*)&h_buf, (void*)&cnt};
  hipLaunchCooperativeKernel((const void*)lstm_rec, dim3(256), dim3(512), args, 0, stream);
}

// Round 6
// 3186.987 us; speedup vs baseline: 1.2181x; 1.0543x over previous
//
#include <hip/hip_runtime.h>
#include <stdint.h>

// LSTM: B=32, S=1024, I=H=512, 4H=2048
// Phase 1: x_gates = x @ W_ih^T + (b_ih + b_hh)   [bf16 MFMA GEMM]
// Phase 2: persistent cooperative kernel, 8 groups x 32 WGs x 512 threads.
//   r5 post-mortem: VGPR=60 with a 16xf32x4 asm pin is only possible if W
//   lives in AGPRs (unified file; accvgpr spill = 1 VALU op, no memory) ->
//   scratch-traffic theory dead. FETCH=531MB == 4x the 134MB xg array: xg is
//   read in 32B granules and consecutive blockIdx (default round-robin) puts
//   the 4 WGs sharing each 128B line on 4 DIFFERENT XCDs' L2s.
//   r6: (a) XCD swizzle g=blockIdx&7 so each group's 32 WGs share one XCD ->
//   xg lines fetched once; (b) fuse reduce+gates phases: tid<64 wave sums
//   scratch directly for all 4 gates (gates_lds + one barrier removed,
//   4 barriers/step). Counter/drain/spin protocol byte-identical to r2/r4/r5.

typedef __attribute__((ext_vector_type(8))) short bf16x8;
typedef __attribute__((ext_vector_type(4))) float f32x4;

__device__ __forceinline__ unsigned short f2bf(float f) {
  union { float f; unsigned u; } v; v.f = f;
  unsigned r = (v.u + 0x7fffu + ((v.u >> 16) & 1u)) >> 16;  // RNE
  return (unsigned short)r;
}
__device__ __forceinline__ float bf2f(unsigned short h) {
  union { unsigned u; float f; } v; v.u = ((unsigned)h) << 16;
  return v.f;
}

__global__ __launch_bounds__(256) void cvt_bf16(const float* __restrict__ in,
                                                unsigned short* __restrict__ out, int n) {
  int i = (blockIdx.x * 256 + threadIdx.x) * 4;
  if (i >= n) return;
  float4 v = *(const float4*)(in + i);
  ushort4 o;
  o.x = f2bf(v.x); o.y = f2bf(v.y); o.z = f2bf(v.z); o.w = f2bf(v.w);
  *(ushort4*)(out + i) = o;
}

// C[m][n] = sum_k A[m][k]*B[n][k] + b_ih[n] + b_hh[n], stored bf16.
__global__ __launch_bounds__(256) void gemm_xg(const unsigned short* __restrict__ A,
                                               const unsigned short* __restrict__ Bw,
                                               const float* __restrict__ b_ih,
                                               const float* __restrict__ b_hh,
                                               unsigned short* __restrict__ xg) {
  __shared__ unsigned short Asub[128][32];
  __shared__ unsigned short Bsub[128][32];
  const int tid = threadIdx.x;
  const int mb = blockIdx.x >> 4;
  const int nb = blockIdx.x & 15;
  const int wv = tid >> 6, ln = tid & 63;
  const int wr = wv >> 1, wc = wv & 1;
  const int lrow = tid >> 1;
  const int lseg = (tid & 1) * 16;

  const unsigned short* Ag = A + (size_t)(mb * 128 + lrow) * 512 + lseg;
  const unsigned short* Bg = Bw + (size_t)(nb * 128 + lrow) * 512 + lseg;

  f32x4 acc[4][4] = {};
  const int frow = ln & 15;
  const int kq = (ln >> 4) * 8;

  for (int k0 = 0; k0 < 512; k0 += 32) {
    uint4 a0 = *(const uint4*)(Ag + k0);
    uint4 a1 = *(const uint4*)(Ag + k0 + 8);
    uint4 b0 = *(const uint4*)(Bg + k0);
    uint4 b1 = *(const uint4*)(Bg + k0 + 8);
    __syncthreads();
    *(uint4*)&Asub[lrow][lseg]     = a0;
    *(uint4*)&Asub[lrow][lseg + 8] = a1;
    *(uint4*)&Bsub[lrow][lseg]     = b0;
    *(uint4*)&Bsub[lrow][lseg + 8] = b1;
    __syncthreads();
    bf16x8 af[4], bfr[4];
#pragma unroll
    for (int mi = 0; mi < 4; ++mi)
      af[mi] = *(const bf16x8*)&Asub[wr * 64 + mi * 16 + frow][kq];
#pragma unroll
    for (int ni = 0; ni < 4; ++ni)
      bfr[ni] = *(const bf16x8*)&Bsub[wc * 64 + ni * 16 + frow][kq];
#pragma unroll
    for (int mi = 0; mi < 4; ++mi)
#pragma unroll
      for (int ni = 0; ni < 4; ++ni)
        acc[mi][ni] = __builtin_amdgcn_mfma_f32_16x16x32_bf16(af[mi], bfr[ni], acc[mi][ni], 0, 0, 0);
  }

  const int col0 = nb * 128 + wc * 64 + frow;
  float bias[4];
#pragma unroll
  for (int ni = 0; ni < 4; ++ni)
    bias[ni] = b_ih[col0 + ni * 16] + b_hh[col0 + ni * 16];

#pragma unroll
  for (int mi = 0; mi < 4; ++mi) {
    const int m0 = mb * 128 + wr * 64 + mi * 16 + (ln >> 4) * 4;
#pragma unroll
    for (int ni = 0; ni < 4; ++ni) {
#pragma unroll
      for (int rr = 0; rr < 4; ++rr) {
        float v = acc[mi][ni][rr] + bias[ni];
        xg[(size_t)(m0 + rr) * 2048 + col0 + ni * 16] = f2bf(v);
      }
    }
  }
}

// One 4-wide k-chunk of the four batch dot-products.
#define FMA_BLK(q, WV)                                                        \
  do {                                                                        \
    f32x4 ha = *(const f32x4*)&h_lds[kcb + (q) * 4];                          \
    f32x4 hb = *(const f32x4*)&h_lds[512 + kcb + (q) * 4];                    \
    f32x4 hc = *(const f32x4*)&h_lds[1024 + kcb + (q) * 4];                   \
    f32x4 hd = *(const f32x4*)&h_lds[1536 + kcb + (q) * 4];                   \
    acc0 = fmaf(WV.x, ha.x, acc0); acc0 = fmaf(WV.y, ha.y, acc0);             \
    acc0 = fmaf(WV.z, ha.z, acc0); acc0 = fmaf(WV.w, ha.w, acc0);             \
    acc1 = fmaf(WV.x, hb.x, acc1); acc1 = fmaf(WV.y, hb.y, acc1);             \
    acc1 = fmaf(WV.z, hb.z, acc1); acc1 = fmaf(WV.w, hb.w, acc1);             \
    acc2 = fmaf(WV.x, hc.x, acc2); acc2 = fmaf(WV.y, hc.y, acc2);             \
    acc2 = fmaf(WV.z, hc.z, acc2); acc2 = fmaf(WV.w, hc.w, acc2);             \
    acc3 = fmaf(WV.x, hd.x, acc3); acc3 = fmaf(WV.y, hd.y, acc3);             \
    acc3 = fmaf(WV.z, hd.z, acc3); acc3 = fmaf(WV.w, hd.w, acc3);             \
  } while (0)

// Persistent recurrent kernel. Grid = 256 WGs (8 groups x 32), 512 threads.
// XCD-swizzled: group g = blockIdx&7 (all its 32 WGs on one XCD under the
// round-robin dispatch heuristic), w = blockIdx>>3 owns h-indices
// [16w,16w+16) -> 64 gate-rows. Thread (kc=tid>>6, r=tid&63) holds
// W_hh[grow(r)][kc*64 .. +64) in 16 named f32x4 registers (or AGPRs).
__global__ __launch_bounds__(512, 1) void lstm_rec(const unsigned short* __restrict__ xg,
                                                   const float* __restrict__ W_hh,
                                                   const float* __restrict__ h0,
                                                   const float* __restrict__ c0,
                                                   float* __restrict__ out,
                                                   float* __restrict__ hn,
                                                   float* __restrict__ cn,
                                                   float* h_buf,        // [2][32][512]
                                                   unsigned int* cnt) { // [8], stride 64 uints
  __shared__ float h_lds[2048];
  __shared__ float scratch[2240];      // [batch(4)@560][kc(8)@68][row(64)]
  __shared__ float c_lds[64];

  const int tid = threadIdx.x;   // 0..511
  const int g = blockIdx.x & 7;  // XCD swizzle: group g on XCD g
  const int w = blockIdx.x >> 3; // 0..31
  const int gb0 = g * 4;
  const int kc = tid >> 6;       // 0..7: 64-wide k-chunk
  const int r = tid & 63;        // row within WG's 64 rows
  const int grow = (r >> 4) * 512 + w * 16 + (r & 15);
  const int kcb = kc * 64;
  unsigned int* my_cnt = cnt + g * 64;  // 256B stride: no false sharing

  // One-time W_hh slice load into 16 NAMED f32x4 values; single asm pin
  // keeps the loads hoisted out of the t-loop (spill target is AGPRs, which
  // is a 1-op reload, not memory).
  const float* wp = W_hh + (size_t)grow * 512 + kcb;
  f32x4 W0  = *(const f32x4*)(wp + 0),  W1  = *(const f32x4*)(wp + 4);
  f32x4 W2  = *(const f32x4*)(wp + 8),  W3  = *(const f32x4*)(wp + 12);
  f32x4 W4  = *(const f32x4*)(wp + 16), W5  = *(const f32x4*)(wp + 20);
  f32x4 W6  = *(const f32x4*)(wp + 24), W7  = *(const f32x4*)(wp + 28);
  f32x4 W8  = *(const f32x4*)(wp + 32), W9  = *(const f32x4*)(wp + 36);
  f32x4 W10 = *(const f32x4*)(wp + 40), W11 = *(const f32x4*)(wp + 44);
  f32x4 W12 = *(const f32x4*)(wp + 48), W13 = *(const f32x4*)(wp + 52);
  f32x4 W14 = *(const f32x4*)(wp + 56), W15 = *(const f32x4*)(wp + 60);
  asm volatile("" : "+v"(W0), "+v"(W1), "+v"(W2), "+v"(W3),
                    "+v"(W4), "+v"(W5), "+v"(W6), "+v"(W7),
                    "+v"(W8), "+v"(W9), "+v"(W10), "+v"(W11),
                    "+v"(W12), "+v"(W13), "+v"(W14), "+v"(W15));

  {
    *(float4*)&h_lds[tid * 4] = *(const float4*)(h0 + gb0 * 512 + tid * 4);
    if (tid < 64) {
      int jj = tid & 15, bb = tid >> 4;
      c_lds[bb * 16 + jj] = c0[(gb0 + bb) * 512 + w * 16 + jj];
    }
  }
  __syncthreads();

  for (int t = 0; t < 1024; ++t) {
    // Gate wave's xg loads issued at loop top, consumed after the FMA loop
    // and barrier -> HBM/L2 latency hidden under compute.
    float xgi = 0.f, xgf = 0.f, xgc = 0.f, xgo = 0.f;
    if (tid < 64) {
      const int jj = tid & 15, bb = tid >> 4;
      const size_t rowbase = (size_t)((gb0 + bb) * 1024 + t) * 2048 + w * 16 + jj;
      xgi = bf2f(xg[rowbase]);
      xgf = bf2f(xg[rowbase + 512]);
      xgc = bf2f(xg[rowbase + 1024]);
      xgo = bf2f(xg[rowbase + 1536]);
    }

    float acc0 = 0.f, acc1 = 0.f, acc2 = 0.f, acc3 = 0.f;
    FMA_BLK(0, W0);   FMA_BLK(1, W1);   FMA_BLK(2, W2);   FMA_BLK(3, W3);
    FMA_BLK(4, W4);   FMA_BLK(5, W5);   FMA_BLK(6, W6);   FMA_BLK(7, W7);
    FMA_BLK(8, W8);   FMA_BLK(9, W9);   FMA_BLK(10, W10); FMA_BLK(11, W11);
    FMA_BLK(12, W12); FMA_BLK(13, W13); FMA_BLK(14, W14); FMA_BLK(15, W15);

    // scratch[b][kc][r], strides 560/68: writes lane-consecutive (no
    // conflict); gate-wave reads land 2-way max (free).
    scratch[0 * 560 + kc * 68 + r] = acc0;
    scratch[1 * 560 + kc * 68 + r] = acc1;
    scratch[2 * 560 + kc * 68 + r] = acc2;
    scratch[3 * 560 + kc * 68 + r] = acc3;
    __syncthreads();  // scratch ready

    if (tid < 64) {
      const int jj = tid & 15, bb = tid >> 4;
      const float* sb = &scratch[bb * 560];
      float gi = xgi, gf = xgf, gc = xgc, go = xgo;
#pragma unroll
      for (int q = 0; q < 8; ++q) {
        const float* sq = sb + q * 68;
        gi += sq[jj];
        gf += sq[16 + jj];
        gc += sq[32 + jj];
        go += sq[48 + jj];
      }
      float ig = 1.f / (1.f + __expf(-gi));
      float fg = 1.f / (1.f + __expf(-gf));
      float gt = tanhf(gc);
      float og = 1.f / (1.f + __expf(-go));
      float c = fmaf(fg, c_lds[bb * 16 + jj], ig * gt);
      c_lds[bb * 16 + jj] = c;
      float hv = og * tanhf(c);
      out[(size_t)((gb0 + bb) * 1024 + t) * 512 + w * 16 + jj] = hv;
      __hip_atomic_store(&h_buf[((t + 1) & 1) * 16384 + (gb0 + bb) * 512 + w * 16 + jj], hv,
                         __ATOMIC_RELAXED, __HIP_MEMORY_SCOPE_AGENT);
      if (t == 1023) {
        hn[(gb0 + bb) * 512 + w * 16 + jj] = hv;
        cn[(gb0 + bb) * 512 + w * 16 + jj] = c;
      }
    }
    __syncthreads();  // s_waitcnt vmcnt(0) before s_barrier: h stores are at LLC

    if (t < 1023) {
      if (tid == 0) {
        __hip_atomic_fetch_add(my_cnt, 1u, __ATOMIC_RELAXED, __HIP_MEMORY_SCOPE_AGENT);
        const unsigned target = 32u * (unsigned)(t + 1);
        while (__hip_atomic_load(my_cnt, __ATOMIC_RELAXED, __HIP_MEMORY_SCOPE_AGENT) < target)
          __builtin_amdgcn_s_sleep(2);
      }
      __syncthreads();
      // Stage next h into LDS; 8-byte relaxed atomic loads (2 VMEM ops/thread).
      const unsigned long long* hb =
          (const unsigned long long*)(h_buf + ((t + 1) & 1) * 16384 + gb0 * 512 + tid * 4);
      unsigned long long v0 = __hip_atomic_load(hb,     __ATOMIC_RELAXED, __HIP_MEMORY_SCOPE_AGENT);
      unsigned long long v1 = __hip_atomic_load(hb + 1, __ATOMIC_RELAXED, __HIP_MEMORY_SCOPE_AGENT);
      *(unsigned long long*)&h_lds[tid * 4]     = v0;
      *(unsigned long long*)&h_lds[tid * 4 + 2] = v1;
      __syncthreads();
    }
  }
}

extern "C" void kernel_launch(void* const* d_in, const int* in_sizes, int n_in,
                              void* d_out, int out_size, void* d_ws, size_t ws_size,
                              hipStream_t stream) {
  const float* x    = (const float*)d_in[0];
  const float* W_ih = (const float*)d_in[1];
  const float* W_hh = (const float*)d_in[2];
  const float* b_ih = (const float*)d_in[3];
  const float* b_hh = (const float*)d_in[4];
  const float* h0   = (const float*)d_in[5];
  const float* c0   = (const float*)d_in[6];
  float* out = (float*)d_out;
  float* hn = out + (size_t)32 * 1024 * 512;
  float* cn = hn + 32 * 512;

  uint8_t* ws = (uint8_t*)d_ws;
  unsigned short* xg   = (unsigned short*)ws;                   // 134,217,728 B
  unsigned short* x_bf = (unsigned short*)(ws + 134217728u);    //  33,554,432 B
  unsigned short* w_bf = (unsigned short*)(ws + 167772160u);    //   2,097,152 B
  float* h_buf         = (float*)(ws + 169869312u);             //     131,072 B
  unsigned int* cnt    = (unsigned int*)(ws + 170000384u);      //  8 * 256 B

  hipMemsetAsync(cnt, 0, 8 * 256, stream);
  cvt_bf16<<<dim3(16384), dim3(256), 0, stream>>>(x, x_bf, 16777216);
  cvt_bf16<<<dim3(1024), dim3(256), 0, stream>>>(W_ih, w_bf, 1048576);
  gemm_xg<<<dim3(4096), dim3(256), 0, stream>>>(x_bf, w_bf, b_ih, b_hh, xg);

  void* args[] = {(void*)&xg, (void*)&W_hh, (void*)&h0, (void*)&c0,
                  (void*)&out, (void*)&hn, (void*)&cn, (void*)&h_buf, (void*)&cnt};
  hipLaunchCooperativeKernel((const void*)lstm_rec, dim3(256), dim3(512), args, 0, stream);
}